// Round 2
// baseline (14627.385 us; speedup 1.0000x reference)
//
#include <hip/hip_runtime.h>
#include <math.h>

#define NB 8      // batch
#define SEQ 512   // LD == LE
#define DIM 512   // D
#define NH 8
#define HD 64
#define FFD 2048
#define NLAYER 6

// ---------------- embedding + sinusoidal position ----------------
__global__ __launch_bounds__(256) void embed_kernel(
    const int* __restrict__ dec, const float* __restrict__ emb, float* __restrict__ X)
{
    int idx = blockIdx.x * 256 + threadIdx.x;   // over NB*SEQ*DIM
    int d  = idx & (DIM - 1);
    int row = idx >> 9;           // b*SEQ + l
    int l  = row & (SEQ - 1);
    int tok = dec[row];
    double e = (double)(2 * (d >> 1)) / (double)DIM;
    double ang = (double)(l + 1) * pow(10000.0, -e);
    float pv = (float)((d & 1) ? cos(ang) : sin(ang));
    X[idx] = emb[(size_t)tok * DIM + d] + pv;
}

__global__ __launch_bounds__(256) void copy_kernel(const float* __restrict__ s, float* __restrict__ d)
{
    int i = blockIdx.x * 256 + threadIdx.x;
    d[i] = s[i];
}

// ---------------- GEMM: C[M,N] = A[M,K] * W[N,K]^T + bias, optional relu ----
__global__ __launch_bounds__(256) void gemm_nt(
    const float* __restrict__ A, const float* __restrict__ W,
    const float* __restrict__ bias, float* __restrict__ C,
    int M, int N, int K, int relu)
{
    __shared__ float As[16][68];
    __shared__ float Ws[16][68];
    const int tid = threadIdx.x;
    const int tx = tid & 15, ty = tid >> 4;
    const int m0 = blockIdx.y * 64, n0 = blockIdx.x * 64;
    float acc[4][4] = {};

    for (int k0 = 0; k0 < K; k0 += 16) {
#pragma unroll
        for (int p = 0; p < 4; ++p) {
            int e = tid + 256 * p;      // 0..1023
            int r = e >> 4, c = e & 15;
            As[c][r] = A[(size_t)(m0 + r) * K + k0 + c];
            Ws[c][r] = W[(size_t)(n0 + r) * K + k0 + c];
        }
        __syncthreads();
#pragma unroll
        for (int kk = 0; kk < 16; ++kk) {
            const float4 a4 = *(const float4*)&As[kk][ty * 4];
            const float4 w4 = *(const float4*)&Ws[kk][tx * 4];
            float av[4] = {a4.x, a4.y, a4.z, a4.w};
            float wv[4] = {w4.x, w4.y, w4.z, w4.w};
#pragma unroll
            for (int i = 0; i < 4; ++i)
#pragma unroll
                for (int j = 0; j < 4; ++j)
                    acc[i][j] += av[i] * wv[j];
        }
        __syncthreads();
    }

    float bv[4];
#pragma unroll
    for (int j = 0; j < 4; ++j) bv[j] = bias[n0 + tx * 4 + j];
#pragma unroll
    for (int i = 0; i < 4; ++i) {
        int m = m0 + ty * 4 + i;
        float4 o;
        float* po = (float*)&o;
#pragma unroll
        for (int j = 0; j < 4; ++j) {
            float v = acc[i][j] + bv[j];
            if (relu) v = fmaxf(v, 0.f);
            po[j] = v;
        }
        *(float4*)&C[(size_t)m * N + n0 + tx * 4] = o;
    }
}

// ---------------- fused attention: scores -> softmax (write w) -> ctx --------
// One block per (q-row, b*h). Lk == 512 always.
__global__ __launch_bounds__(256) void attn_fused(
    const float* __restrict__ Q, const float* __restrict__ Kb, const float* __restrict__ Vb,
    const int* __restrict__ toks, float* __restrict__ Wout, float* __restrict__ CTX,
    int causal)
{
    const int tid = threadIdx.x;
    const int q  = blockIdx.x;
    const int bh = blockIdx.y;
    const int b = bh >> 3, h = bh & 7;

    __shared__ float sq[HD];
    __shared__ float sw[SEQ];
    __shared__ float red[256];

    if (tid < HD) sq[tid] = Q[((size_t)(b * SEQ + q)) * DIM + h * HD + tid];
    __syncthreads();

    float s[2];
    float mx = -3.0e38f;
#pragma unroll
    for (int t = 0; t < 2; ++t) {
        int k = tid + t * 256;
        const float* kp = &Kb[((size_t)(b * SEQ + k)) * DIM + h * HD];
        float acc = 0.f;
#pragma unroll
        for (int d = 0; d < HD; ++d) acc += sq[d] * kp[d];
        acc *= 0.125f;
        bool masked = (toks[b * SEQ + k] == 0) || (causal && (k > q));
        if (masked) acc = -1e9f;
        s[t] = acc;
        mx = fmaxf(mx, acc);
    }

    red[tid] = mx; __syncthreads();
    for (int st = 128; st; st >>= 1) { if (tid < st) red[tid] = fmaxf(red[tid], red[tid + st]); __syncthreads(); }
    mx = red[0]; __syncthreads();

    float lsum = 0.f;
#pragma unroll
    for (int t = 0; t < 2; ++t) { s[t] = expf(s[t] - mx); lsum += s[t]; }
    red[tid] = lsum; __syncthreads();
    for (int st = 128; st; st >>= 1) { if (tid < st) red[tid] += red[tid + st]; __syncthreads(); }
    float inv = 1.f / red[0];
    __syncthreads();   // red reused below

    float* wp = Wout + ((size_t)(b * NH + h) * SEQ + q) * SEQ;
#pragma unroll
    for (int t = 0; t < 2; ++t) {
        int k = tid + t * 256;
        float wv = s[t] * inv;
        sw[k] = wv;
        wp[k] = wv;
    }
    __syncthreads();

    // ctx: 4 chunks of 128 k-steps; thread = (d = tid&63, chunk = tid>>6)
    const int d = tid & 63, ch = tid >> 6;
    const float* vp = &Vb[((size_t)(b * SEQ + ch * 128)) * DIM + h * HD + d];
    float acc = 0.f;
#pragma unroll 4
    for (int kk = 0; kk < 128; ++kk) acc += sw[ch * 128 + kk] * vp[(size_t)kk * DIM];
    red[tid] = acc; __syncthreads();
    if (tid < 64)
        CTX[((size_t)(b * SEQ + q)) * DIM + h * HD + tid] =
            red[tid] + red[tid + 64] + red[tid + 128] + red[tid + 192];
}

// ---------------- residual add + layernorm ----------------
__global__ __launch_bounds__(256) void add_ln(
    const float* __restrict__ Xin, const float* __restrict__ O,
    const float* __restrict__ g, const float* __restrict__ bt,
    float* Xout)
{
    const int row = blockIdx.x, tid = threadIdx.x;
    __shared__ float red[256];
    const size_t base = (size_t)row * DIM;
    float v0 = Xin[base + tid] + O[base + tid];
    float v1 = Xin[base + tid + 256] + O[base + tid + 256];
    red[tid] = v0 + v1; __syncthreads();
    for (int st = 128; st; st >>= 1) { if (tid < st) red[tid] += red[tid + st]; __syncthreads(); }
    float mean = red[0] * (1.f / 512.f); __syncthreads();
    red[tid] = v0 * v0 + v1 * v1; __syncthreads();
    for (int st = 128; st; st >>= 1) { if (tid < st) red[tid] += red[tid + st]; __syncthreads(); }
    float var = red[0] * (1.f / 512.f) - mean * mean;
    float rst = rsqrtf(var + 1e-5f);
    Xout[base + tid]       = (v0 - mean) * rst * g[tid]       + bt[tid];
    Xout[base + tid + 256] = (v1 - mean) * rst * g[tid + 256] + bt[tid + 256];
}

// ---------------- host orchestration ----------------
extern "C" void kernel_launch(void* const* d_in, const int* in_sizes, int n_in,
                              void* d_out, int out_size, void* d_ws, size_t ws_size,
                              hipStream_t stream)
{
    const int*   dec     = (const int*)d_in[0];
    const int*   enc     = (const int*)d_in[1];
    const float* enc_out = (const float*)d_in[2];
    const float* emb     = (const float*)d_in[3];
    const float* sa_wq = (const float*)d_in[4];
    const float* sa_wk = (const float*)d_in[5];
    const float* sa_wv = (const float*)d_in[6];
    const float* sa_wo = (const float*)d_in[7];
    const float* sa_bq = (const float*)d_in[8];
    const float* sa_bk = (const float*)d_in[9];
    const float* sa_bv = (const float*)d_in[10];
    const float* sa_bo = (const float*)d_in[11];
    const float* sa_g  = (const float*)d_in[12];
    const float* sa_b  = (const float*)d_in[13];
    const float* ca_wq = (const float*)d_in[14];
    const float* ca_wk = (const float*)d_in[15];
    const float* ca_wv = (const float*)d_in[16];
    const float* ca_wo = (const float*)d_in[17];
    const float* ca_bq = (const float*)d_in[18];
    const float* ca_bk = (const float*)d_in[19];
    const float* ca_bv = (const float*)d_in[20];
    const float* ca_bo = (const float*)d_in[21];
    const float* ca_g  = (const float*)d_in[22];
    const float* ca_b  = (const float*)d_in[23];
    const float* ffn_w1 = (const float*)d_in[24];
    const float* ffn_b1 = (const float*)d_in[25];
    const float* ffn_w2 = (const float*)d_in[26];
    const float* ffn_b2 = (const float*)d_in[27];
    const float* ffn_g  = (const float*)d_in[28];
    const float* ffn_b  = (const float*)d_in[29];

    float* out = (float*)d_out;
    const size_t NTOK = (size_t)NB * SEQ;        // 4096 rows
    const size_t NELT = NTOK * DIM;              // 2,097,152
    const size_t DD = (size_t)DIM * DIM;         // 262,144

    float* X    = (float*)d_ws;
    float* A1   = X    + NELT;    // Q   (FFN hidden overlays A1..A4)
    float* A2   = A1   + NELT;    // K
    float* A3   = A2   + NELT;    // V
    float* A4   = A3   + NELT;    // CTX
    float* A5   = A4   + NELT;    // attn/FFN output before LN
    float* Fb   = A1;             // [4096, 2048] fp32 FFN hidden

    const size_t SA_BASE = NELT;                          // 2,097,152
    const size_t PER_L   = (size_t)NB * NH * SEQ * SEQ;   // 16,777,216
    const size_t CA_BASE = SA_BASE + (size_t)NLAYER * PER_L;

    dim3 blk(256);
    dim3 g_elem((unsigned)(NELT / 256));
    dim3 g_gemm_d(DIM / 64, (unsigned)(NTOK / 64));   // (8, 64)
    dim3 g_gemm_f(FFD / 64, (unsigned)(NTOK / 64));   // (32, 64)
    dim3 g_attn(SEQ, NB * NH);                        // (512, 64)

    embed_kernel<<<g_elem, blk, 0, stream>>>(dec, emb, X);

    for (int l = 0; l < NLAYER; ++l) {
        // ---- self-attention ----
        gemm_nt<<<g_gemm_d, blk, 0, stream>>>(X, sa_wq + l * DD, sa_bq + l * DIM, A1, (int)NTOK, DIM, DIM, 0);
        gemm_nt<<<g_gemm_d, blk, 0, stream>>>(X, sa_wk + l * DD, sa_bk + l * DIM, A2, (int)NTOK, DIM, DIM, 0);
        gemm_nt<<<g_gemm_d, blk, 0, stream>>>(X, sa_wv + l * DD, sa_bv + l * DIM, A3, (int)NTOK, DIM, DIM, 0);
        attn_fused<<<g_attn, blk, 0, stream>>>(A1, A2, A3, dec, out + SA_BASE + (size_t)l * PER_L, A4, 1);
        gemm_nt<<<g_gemm_d, blk, 0, stream>>>(A4, sa_wo + l * DD, sa_bo + l * DIM, A5, (int)NTOK, DIM, DIM, 0);
        add_ln<<<dim3((unsigned)NTOK), blk, 0, stream>>>(X, A5, sa_g + l * DIM, sa_b + l * DIM, X);

        // ---- cross-attention ----
        gemm_nt<<<g_gemm_d, blk, 0, stream>>>(X,       ca_wq + l * DD, ca_bq + l * DIM, A1, (int)NTOK, DIM, DIM, 0);
        gemm_nt<<<g_gemm_d, blk, 0, stream>>>(enc_out, ca_wk + l * DD, ca_bk + l * DIM, A2, (int)NTOK, DIM, DIM, 0);
        gemm_nt<<<g_gemm_d, blk, 0, stream>>>(enc_out, ca_wv + l * DD, ca_bv + l * DIM, A3, (int)NTOK, DIM, DIM, 0);
        attn_fused<<<g_attn, blk, 0, stream>>>(A1, A2, A3, enc, out + CA_BASE + (size_t)l * PER_L, A4, 0);
        gemm_nt<<<g_gemm_d, blk, 0, stream>>>(A4, ca_wo + l * DD, ca_bo + l * DIM, A5, (int)NTOK, DIM, DIM, 0);
        add_ln<<<dim3((unsigned)NTOK), blk, 0, stream>>>(X, A5, ca_g + l * DIM, ca_b + l * DIM, X);

        // ---- FFN ----
        gemm_nt<<<g_gemm_f, blk, 0, stream>>>(X,  ffn_w1 + l * (size_t)FFD * DIM, ffn_b1 + l * FFD, Fb, (int)NTOK, FFD, DIM, 1);
        gemm_nt<<<g_gemm_d, blk, 0, stream>>>(Fb, ffn_w2 + l * (size_t)DIM * FFD, ffn_b2 + l * DIM, A5, (int)NTOK, DIM, FFD, 0);
        add_ln<<<dim3((unsigned)NTOK), blk, 0, stream>>>(X, A5, ffn_g + l * DIM, ffn_b + l * DIM, X);
    }

    copy_kernel<<<g_elem, blk, 0, stream>>>(X, out);
}